// Round 6
// baseline (516.606 us; speedup 1.0000x reference)
//
#include <hip/hip_runtime.h>
#include <math.h>

// Problem constants (fixed by reference)
#define BB   2
#define TT   4096            // tokens per batch
#define NT   (BB*TT)         // 8192 total rows
#define DD   1024
#define CQ   128             // k_query dim
#define TK   8               // top_k
#define NCH  16              // s-splits (partial top-8 lists per query)

// ---------------------------------------------------------------------------
// top-8 sorted insert, STRICT comparator: correct vs jax.lax.top_k tie rules
// when candidates arrive in ascending index order.
// ---------------------------------------------------------------------------
__device__ __forceinline__ void topk8_insert_strict(float (&v)[TK], int (&ix)[TK],
                                                    float val, int idx) {
    float cv = val; int ci = idx;
#pragma unroll
    for (int i = 0; i < TK; ++i) {
        bool sw = (cv > v[i]);
        float tv = v[i]; int ti = ix[i];
        v[i]  = sw ? cv : tv;  ix[i] = sw ? ci : ti;
        cv    = sw ? tv : cv;  ci    = sw ? ti : ci;
    }
}

// tie-break-aware insert (for merging lists whose index order is mixed)
__device__ __forceinline__ void topk8_insert(float (&v)[TK], int (&ix)[TK],
                                             float val, int idx) {
    float cv = val; int ci = idx;
#pragma unroll
    for (int i = 0; i < TK; ++i) {
        bool sw = (cv > v[i]) || (cv == v[i] && ci < ix[i]);
        float tv = v[i]; int ti = ix[i];
        v[i]  = sw ? cv : tv;  ix[i] = sw ? ci : ti;
        cv    = sw ? tv : cv;  ci    = sw ? ti : ci;
    }
}

// f64 tie-break-aware insert (final exact ranking)
__device__ __forceinline__ void topk8d_insert(double (&v)[TK], int (&ix)[TK],
                                              double val, int idx) {
    double cv = val; int ci = idx;
#pragma unroll
    for (int i = 0; i < TK; ++i) {
        bool sw = (cv > v[i]) || (cv == v[i] && ci < ix[i]);
        double tv = v[i]; int ti = ix[i];
        v[i]  = sw ? cv : tv;  ix[i] = sw ? ci : ti;
        cv    = sw ? tv : cv;  ci    = sw ? ti : ci;
    }
}

// ---------------------------------------------------------------------------
// K1: q = x@Wq + bq ; k = x@Wk + bk   (f32, W broadcast via uniform loads)
// ---------------------------------------------------------------------------
__global__ __launch_bounds__(256) void proj_kernel(
    const float* __restrict__ x,
    const float* __restrict__ Wq, const float* __restrict__ bq,
    const float* __restrict__ Wk, const float* __restrict__ bk,
    float* __restrict__ q, float* __restrict__ k)
{
    int row = blockIdx.x * 256 + threadIdx.x;        // 0..NT-1
    int cc  = blockIdx.y * 16;                       // combined col 0..255
    bool isK = cc >= CQ;
    const float* W    = isK ? Wk : Wq;
    const float* bias = isK ? bk : bq;
    int c0 = isK ? cc - CQ : cc;

    float acc[16];
#pragma unroll
    for (int j = 0; j < 16; ++j) acc[j] = 0.f;

    const float* xr = x + (size_t)row * DD;
    for (int d0 = 0; d0 < DD; d0 += 4) {
        float4 xv = *reinterpret_cast<const float4*>(xr + d0);
        const float* w0 = W + (size_t)d0 * CQ + c0;
#pragma unroll
        for (int j = 0; j < 16; ++j) {
            acc[j] = fmaf(xv.x, w0[j],        acc[j]);
            acc[j] = fmaf(xv.y, w0[CQ + j],   acc[j]);
            acc[j] = fmaf(xv.z, w0[2*CQ + j], acc[j]);
            acc[j] = fmaf(xv.w, w0[3*CQ + j], acc[j]);
        }
    }
    float* outp = (isK ? k : q) + (size_t)row * CQ + c0;
#pragma unroll
    for (int j = 0; j < 16; ++j) outp[j] = acc[j] + bias[c0 + j];
}

// ---------------------------------------------------------------------------
// K1b: gates = sigmoid(x@Wg + bg)   one wave per row
// ---------------------------------------------------------------------------
__global__ __launch_bounds__(256) void gate_kernel(
    const float* __restrict__ x, const float* __restrict__ Wg,
    const float* __restrict__ bg, float* __restrict__ gout)
{
    int wave = threadIdx.x >> 6, lane = threadIdx.x & 63;
    int row  = blockIdx.x * 4 + wave;
    const float* xr = x + (size_t)row * DD;
    float s = 0.f;
#pragma unroll
    for (int i = 0; i < 4; ++i) {
        int d = (i * 64 + lane) * 4;
        float4 xv = *reinterpret_cast<const float4*>(xr + d);
        float4 wv = *reinterpret_cast<const float4*>(Wg + d);
        s = fmaf(xv.x, wv.x, s); s = fmaf(xv.y, wv.y, s);
        s = fmaf(xv.z, wv.z, s); s = fmaf(xv.w, wv.w, s);
    }
#pragma unroll
    for (int off = 32; off; off >>= 1) s += __shfl_xor(s, off);
    if (lane == 0) gout[row] = 1.f / (1.f + expf(-(s + bg[0])));
}

// ---------------------------------------------------------------------------
// K2: sim + candidate top-8, scan fully IN REGISTERS.
// Thread = 1 query x 8 keys. Block = 64 queries x 32-key chunks (8 chunks =
// 256 keys per split). LDS: A[64q][128k] (32KB, k-group XOR q&7-swizzled) +
// B[128k][32s] (16KB, s-group XOR k4&7-swizzled) = 48KB -> 3 blocks/CU.
// A-read: 16 rows, 2 per bank-group (2-way, free). B-read: 4 distinct addrs,
// 16-lane broadcast (conflict-free). No sim-tile LDS round-trip.
// Candidates only; exact f64 ranking in K3.
// ---------------------------------------------------------------------------
__global__ __launch_bounds__(256, 3) void simtopk_kernel(
    const float* __restrict__ q, const float* __restrict__ kmat,
    const float* __restrict__ gates, const float* __restrict__ am,
    float* __restrict__ pv, int* __restrict__ pi)
{
    __shared__ float Alds[64 * 128];   // 32 KB
    __shared__ float Blds[128 * 32];   // 16 KB

    const int tid  = threadIdx.x;
    const int qloc = ((tid >> 6) << 4) | (tid & 15);   // 0..63 (16 q per wave)
    const int txg  = (tid >> 4) & 3;                   // key slice 0..3
    const int qt   = blockIdx.x;                       // 0..127
    const int sp   = blockIdx.y;                       // 0..15
    const int t0   = qt * 64;
    const int b    = t0 >> 12;
    const int tq   = t0 + qloc;

    // staging roles
    const int c4  = tid & 31;          // float4-column within 128-dim
    const int rr0 = tid >> 5;          // 0..7

    const float gate = gates[tq];
    const float mq   = am[tq];
    const float sgq  = 0.08838834764831845f * gate;   // scale * gate
    const float mneg = -1e9f * gate;

    float tv[TK]; int tix[TK];
#pragma unroll
    for (int j = 0; j < TK; ++j) { tv[j] = -3.0e38f; tix[j] = 0; }

    // ---- stage A (64 q-rows, [q][k] with k-group ^= q&7) ----
#pragma unroll
    for (int pass = 0; pass < 8; ++pass) {
        int ql = rr0 + pass * 8;
        float4 g4 = *reinterpret_cast<const float4*>(
            q + (size_t)(t0 + ql) * CQ + c4 * 4);
        int pg = c4 ^ (ql & 7);
        *reinterpret_cast<float4*>(&Alds[ql * 128 + pg * 4]) = g4;
    }

    // ---- stage B chunk 0 ([k][s] with s-group ^= (k>>2)&7) ----
    {
        const float* kb = kmat + (size_t)(b * TT + sp * 256) * CQ;
#pragma unroll
        for (int pass = 0; pass < 4; ++pass) {
            int s = rr0 + pass * 8;
            float4 kv = *reinterpret_cast<const float4*>(kb + (size_t)s * CQ + c4 * 4);
            int sg = (s >> 2) ^ (c4 & 7);
            int so = (sg << 2) + (s & 3);
            Blds[(c4 * 4 + 0) * 32 + so] = kv.x;
            Blds[(c4 * 4 + 1) * 32 + so] = kv.y;
            Blds[(c4 * 4 + 2) * 32 + so] = kv.z;
            Blds[(c4 * 4 + 3) * 32 + so] = kv.w;
        }
    }
    __syncthreads();

    const float* arow = &Alds[qloc * 128];
    const int    qm7  = qloc & 7;

    for (int ck = 0; ck < 8; ++ck) {
        // ---- GEMM: 8 accumulator chains over K=128 ----
        float acc[8] = {0.f,0.f,0.f,0.f,0.f,0.f,0.f,0.f};
#pragma unroll 8
        for (int k4 = 0; k4 < 32; ++k4) {
            float4 aq = *reinterpret_cast<const float4*>(arow + ((k4 ^ qm7) << 2));
            int g0 = ((txg * 2 + 0) ^ (k4 & 7)) << 2;
            int g1 = ((txg * 2 + 1) ^ (k4 & 7)) << 2;
            const float* brow = &Blds[k4 * 128];   // 4 k-rows of 32
#pragma unroll
            for (int kk = 0; kk < 4; ++kk) {
                float4 b0 = *reinterpret_cast<const float4*>(brow + kk * 32 + g0);
                float4 b1 = *reinterpret_cast<const float4*>(brow + kk * 32 + g1);
                float a = (kk == 0) ? aq.x : (kk == 1) ? aq.y : (kk == 2) ? aq.z : aq.w;
                acc[0] = fmaf(a, b0.x, acc[0]);
                acc[1] = fmaf(a, b0.y, acc[1]);
                acc[2] = fmaf(a, b0.z, acc[2]);
                acc[3] = fmaf(a, b0.w, acc[3]);
                acc[4] = fmaf(a, b1.x, acc[4]);
                acc[5] = fmaf(a, b1.y, acc[5]);
                acc[6] = fmaf(a, b1.z, acc[6]);
                acc[7] = fmaf(a, b1.w, acc[7]);
            }
        }
        __syncthreads();   // all GEMM reads of Blds done

        // ---- issue next chunk's staging loads early (T14-lite) ----
        float4 breg[4];
        if (ck < 7) {
            const float* kb = kmat + (size_t)(b * TT + sp * 256 + (ck + 1) * 32) * CQ;
#pragma unroll
            for (int pass = 0; pass < 4; ++pass) {
                int s = rr0 + pass * 8;
                breg[pass] = *reinterpret_cast<const float4*>(
                    kb + (size_t)s * CQ + c4 * 4);
            }
        }

        // ---- scan: in-register, candidates ascend in s ----
        {
            int sb = sp * 256 + ck * 32 + txg * 8;       // within-batch key base
            float4 a40 = *reinterpret_cast<const float4*>(am + b * TT + sb);
            float4 a41 = *reinterpret_cast<const float4*>(am + b * TT + sb + 4);
            float val;
            val = (mq * a40.x == 0.f) ? mneg : acc[0] * sgq;
            if (val > tv[TK-1]) topk8_insert_strict(tv, tix, val, sb + 0);
            val = (mq * a40.y == 0.f) ? mneg : acc[1] * sgq;
            if (val > tv[TK-1]) topk8_insert_strict(tv, tix, val, sb + 1);
            val = (mq * a40.z == 0.f) ? mneg : acc[2] * sgq;
            if (val > tv[TK-1]) topk8_insert_strict(tv, tix, val, sb + 2);
            val = (mq * a40.w == 0.f) ? mneg : acc[3] * sgq;
            if (val > tv[TK-1]) topk8_insert_strict(tv, tix, val, sb + 3);
            val = (mq * a41.x == 0.f) ? mneg : acc[4] * sgq;
            if (val > tv[TK-1]) topk8_insert_strict(tv, tix, val, sb + 4);
            val = (mq * a41.y == 0.f) ? mneg : acc[5] * sgq;
            if (val > tv[TK-1]) topk8_insert_strict(tv, tix, val, sb + 5);
            val = (mq * a41.z == 0.f) ? mneg : acc[6] * sgq;
            if (val > tv[TK-1]) topk8_insert_strict(tv, tix, val, sb + 6);
            val = (mq * a41.w == 0.f) ? mneg : acc[7] * sgq;
            if (val > tv[TK-1]) topk8_insert_strict(tv, tix, val, sb + 7);
        }

        // ---- write staged B ----
        if (ck < 7) {
#pragma unroll
            for (int pass = 0; pass < 4; ++pass) {
                int s = rr0 + pass * 8;
                int sg = (s >> 2) ^ (c4 & 7);
                int so = (sg << 2) + (s & 3);
                Blds[(c4 * 4 + 0) * 32 + so] = breg[pass].x;
                Blds[(c4 * 4 + 1) * 32 + so] = breg[pass].y;
                Blds[(c4 * 4 + 2) * 32 + so] = breg[pass].z;
                Blds[(c4 * 4 + 3) * 32 + so] = breg[pass].w;
            }
        }
        __syncthreads();
    }

    // ---- merge 4 key-slices per query (LDS reused, stride 9 = ~2-way) ----
    float* mv = Blds;                       // 256*9 = 2304 <= 4096 floats
    int*   mi = (int*)Alds;
    int slot = qloc * 4 + txg;
#pragma unroll
    for (int j = 0; j < TK; ++j) { mv[slot * 9 + j] = tv[j]; mi[slot * 9 + j] = tix[j]; }
    __syncthreads();
    if (txg == 0) {
        for (int u = 1; u < 4; ++u) {
#pragma unroll
            for (int j = 0; j < TK; ++j) {
                float val = mv[(slot + u) * 9 + j];
                int   s   = mi[(slot + u) * 9 + j];
                if (val > tv[TK-1] || (val == tv[TK-1] && s < tix[TK-1]))
                    topk8_insert(tv, tix, val, s);
            }
        }
        int base = (tq * NCH + sp) * TK;
#pragma unroll
        for (int j = 0; j < TK; ++j) { pv[base + j] = tv[j]; pi[base + j] = tix[j]; }
    }
}

// ---------------------------------------------------------------------------
// K3: per query, rescore ALL 128 candidates in f64 (exact ranking), pick
// top-8 tie-aware, write idx (as float) + values, gather x rows.
// ---------------------------------------------------------------------------
__global__ __launch_bounds__(256) void merge_gather_kernel(
    const float* __restrict__ x,  const float* __restrict__ qm,
    const float* __restrict__ kmat, const float* __restrict__ gates,
    const float* __restrict__ am, const int* __restrict__ pi,
    float* __restrict__ out_g, float* __restrict__ out_i,
    float* __restrict__ out_v)
{
    int t = blockIdx.x;
    int b = t >> 12;

    __shared__ float  qrow[CQ];
    __shared__ double sval[NCH * TK];
    __shared__ int    scand[NCH * TK];
    __shared__ int    fidx[TK];

    if (threadIdx.x < 32) {
        *reinterpret_cast<float4*>(qrow + threadIdx.x * 4) =
            *reinterpret_cast<const float4*>(qm + (size_t)t * CQ + threadIdx.x * 4);
    }
    __syncthreads();

    if (threadIdx.x < NCH * TK) {
        int s = pi[(size_t)t * NCH * TK + threadIdx.x];
        const float* kr = kmat + (size_t)(b * TT + s) * CQ;
        double acc = 0.0;
#pragma unroll
        for (int d = 0; d < CQ; d += 4) {
            acc += (double)qrow[d + 0] * (double)kr[d + 0];
            acc += (double)qrow[d + 1] * (double)kr[d + 1];
            acc += (double)qrow[d + 2] * (double)kr[d + 2];
            acc += (double)qrow[d + 3] * (double)kr[d + 3];
        }
        double val;
        float ms  = am[b * TT + s];
        float mqq = am[t];
        if (mqq * ms == 0.f) val = -1e9;
        else                 val = acc * 0.08838834764831845;
        val *= (double)gates[t];
        sval[threadIdx.x]  = val;
        scand[threadIdx.x] = s;
    }
    __syncthreads();

    if (threadIdx.x == 0) {
        double v[TK]; int ix[TK];
#pragma unroll
        for (int j = 0; j < TK; ++j) { v[j] = -1.0e300; ix[j] = 0x7FFFFFFF; }
        for (int c = 0; c < NCH * TK; ++c) {
            double val = sval[c]; int s = scand[c];
            if (val > v[TK-1] || (val == v[TK-1] && s < ix[TK-1]))
                topk8d_insert(v, ix, val, s);
        }
#pragma unroll
        for (int j = 0; j < TK; ++j) {
            out_i[t * TK + j] = (float)ix[j];
            out_v[t * TK + j] = (float)v[j];
            fidx[j] = ix[j];
        }
    }
    __syncthreads();

#pragma unroll
    for (int j = 0; j < TK; ++j) {
        int row = fidx[j];
        float4 val4 = *reinterpret_cast<const float4*>(
            x + ((size_t)(b * TT + row)) * DD + threadIdx.x * 4);
        *reinterpret_cast<float4*>(
            out_g + ((size_t)(t * TK + j)) * DD + threadIdx.x * 4) = val4;
    }
}

// ---------------------------------------------------------------------------
extern "C" void kernel_launch(void* const* d_in, const int* in_sizes, int n_in,
                              void* d_out, int out_size, void* d_ws, size_t ws_size,
                              hipStream_t stream) {
    const float* x  = (const float*)d_in[0];
    const float* am = (const float*)d_in[1];
    const float* Wq = (const float*)d_in[2];
    const float* bq = (const float*)d_in[3];
    const float* Wk = (const float*)d_in[4];
    const float* bk = (const float*)d_in[5];
    const float* Wg = (const float*)d_in[6];
    const float* bg = (const float*)d_in[7];

    float* ws = (float*)d_ws;
    float* q  = ws;                              // NT*CQ      = 1048576
    float* k  = ws + 1048576;                    // NT*CQ      = 1048576
    float* g  = ws + 2097152;                    // NT         = 8192
    float* pv = ws + 2105344;                    // NT*NCH*TK  = 1048576
    int*   pi = (int*)(ws + 3153920);            // NT*NCH*TK  = 1048576

    float* out_g = (float*)d_out;                // [B,T,K,D] = 67108864
    float* out_i = out_g + 67108864;             // [B,T,K]   = 65536 (as float)
    float* out_v = out_i + 65536;                // [B,T,K]   = 65536

    proj_kernel<<<dim3(NT / 256, 16), 256, 0, stream>>>(x, Wq, bq, Wk, bk, q, k);
    gate_kernel<<<NT / 4, 256, 0, stream>>>(x, Wg, bg, g);
    simtopk_kernel<<<dim3(128, NCH), 256, 0, stream>>>(q, k, g, am, pv, pi);
    merge_gather_kernel<<<NT, 256, 0, stream>>>(x, q, k, g, am, pi,
                                                out_g, out_i, out_v);
}